// Round 2
// baseline (72143.842 us; speedup 1.0000x reference)
//
#include <hip/hip_runtime.h>
#include <math.h>

// 2-layer LSTM decoder, H=100, T=8192 encode + F=1024 future steps, fp32.
// TWO persistent blocks (2 CUs), 512 threads each:
//   block 0 : A-group (tid<256, waves 0-3) = layer-1 recurrence -> ring1 (LLC)
//             B-group (tid>=256, waves 4-7) = layer-2 recurrence + y output.
//             B->A feedback (y) is LDS-only (yring + yflag): the serial cycle
//             in the future phase no longer crosses CUs for y.
//   block 1 : A2 = feed-forward pre2 = w_ih2*h1 + biases. ring1 -> ring2 (LLC).
//
// Key structure (sync-latency pass 2):
//  * NO __syncthreads in steady state. A/B groups run DECOUPLED loops (a fixed
//    lockstep lag would force the A->A2->B LLC round trip into every encode
//    iteration). Intra-group h-state exchange uses a monotone per-wave-counter
//    LDS barrier (single-writer counters, min-spin).
//  * Early-fence release: the vmcnt drain certifying step t's ring stores runs
//    at the TOP of iteration t+1 (fence + darr/carr arrive counters); by then
//    the LLC ack has landed under the previous iteration's compute -> the
//    ~500cy store-drain is off the critical path in encode.
//  * 2 waves/SIMD (A+B share SIMDs): one group's LLC stalls are filled by the
//    other group's VALU issue.
//  * Future phase: A and B both compute their local recurrent dot BEFORE
//    waiting on upstream (dot depends only on block-local h).
//  * Spin loops poll RELAXED; one acquire fence on success. Ring/flag stores
//    are write-through agent atomics. Counters monotone <= 9217 -> 0xAA
//    poison sanitizes to 0.

#define HH 100
#define NT 512
#define ROWS 400
#define SPIN_CAP 2000000u

#define OFF_APROG  0
#define OFF_P2PROG 128
#define OFF_BPROG  256
#define OFF_RING   16384

__device__ __forceinline__ float rl(float v, int k) {
    return __int_as_float(__builtin_amdgcn_readlane(__float_as_int(v), k));
}
__device__ __forceinline__ unsigned san(unsigned v) { return v > 0x00FFFFFFu ? 0u : v; }
__device__ __forceinline__ void rel(unsigned* p, unsigned v) {
    __hip_atomic_store(p, v, __ATOMIC_RELEASE, __HIP_MEMORY_SCOPE_AGENT);
}
__device__ __forceinline__ float ld_f(const float* p) {
    return __hip_atomic_load((float*)p, __ATOMIC_RELAXED, __HIP_MEMORY_SCOPE_AGENT);
}
__device__ __forceinline__ void st_wt(float* p, float v) {
    __hip_atomic_store(p, v, __ATOMIC_RELAXED, __HIP_MEMORY_SCOPE_AGENT);
}
__device__ __forceinline__ unsigned ld_lds(const unsigned* p) {
    return __hip_atomic_load(p, __ATOMIC_RELAXED, __HIP_MEMORY_SCOPE_WORKGROUP);
}
__device__ __forceinline__ void st_lds(unsigned* p, unsigned v) {
    __hip_atomic_store(p, v, __ATOMIC_RELAXED, __HIP_MEMORY_SCOPE_WORKGROUP);
}
// Relaxed polls + one acquire fence on success.
__device__ __forceinline__ void wait_ge(unsigned* p, unsigned need, unsigned& cache) {
    if (cache >= need) return;
    unsigned s = 0;
    do {
        cache = san(__hip_atomic_load(p, __ATOMIC_RELAXED, __HIP_MEMORY_SCOPE_AGENT));
    } while (cache < need && ++s < SPIN_CAP);
    __builtin_amdgcn_fence(__ATOMIC_ACQUIRE, "agent");
}
__device__ __forceinline__ void fence_rel_agent() {
    __builtin_amdgcn_fence(__ATOMIC_RELEASE, "agent");   // waits vmcnt(0): drains prior global stores
}
__device__ __forceinline__ void spin_min4(unsigned* arr, unsigned tgt) {
    unsigned s = 0;
    for (;;) {
        unsigned m0 = ld_lds(&arr[0]), m1 = ld_lds(&arr[1]);
        unsigned m2 = ld_lds(&arr[2]), m3 = ld_lds(&arr[3]);
        unsigned m = m0 < m1 ? m0 : m1;
        unsigned n = m2 < m3 ? m2 : m3;
        if ((m < n ? m : n) >= tgt) break;
        if (++s > SPIN_CAP) break;
    }
}
// 4-wave group barrier: monotone per-wave counters, single writer each.
__device__ __forceinline__ void grp_barrier(unsigned* arr, int w, int l, unsigned tgt) {
    __builtin_amdgcn_fence(__ATOMIC_RELEASE, "workgroup");   // lgkm drain: LDS writes visible
    if (l == 0) st_lds(&arr[w], tgt);
    spin_min4(arr, tgt);
    __builtin_amdgcn_fence(__ATOMIC_ACQUIRE, "workgroup");
}
__device__ __forceinline__ float fast_sigm(float x) {
    return __builtin_amdgcn_rcpf(1.0f + __expf(-x));
}
__device__ __forceinline__ float fast_tanh(float x) {
    return fmaf(-2.0f, __builtin_amdgcn_rcpf(1.0f + __expf(2.0f * x)), 1.0f);
}

// accA += dot(w0, h), accB += dot(w1, h); h lane-indexed: hv0 lane k = h[k],
// hv1 lane k = h[64+k] (k<36).
__device__ __forceinline__ void dot2rows(const float* w0, const float* w1,
                                         float hv0, float hv1,
                                         float& accA, float& accB) {
    float a0 = 0.f, a1 = 0.f, b0 = 0.f, b1 = 0.f;
    #pragma unroll
    for (int k = 0; k < 64; k += 2) {
        float h0 = rl(hv0, k), h1 = rl(hv0, k + 1);
        a0 = fmaf(w0[k],     h0, a0);
        a1 = fmaf(w0[k + 1], h1, a1);
        b0 = fmaf(w1[k],     h0, b0);
        b1 = fmaf(w1[k + 1], h1, b1);
    }
    #pragma unroll
    for (int k = 0; k < 36; k += 2) {
        float h0 = rl(hv1, k), h1 = rl(hv1, k + 1);
        a0 = fmaf(w0[64 + k],     h0, a0);
        a1 = fmaf(w0[64 + k + 1], h1, a1);
        b0 = fmaf(w1[64 + k],     h0, b0);
        b1 = fmaf(w1[64 + k + 1], h1, b1);
    }
    accA += (a0 + a1);
    accB += (b0 + b1);
}

extern "C" __global__ void __launch_bounds__(NT, 2)
decoder_kernel(const float* __restrict__ input,
               const float* __restrict__ enc_h,
               const float* __restrict__ enc_c,
               const float* __restrict__ w_ih1,
               const float* __restrict__ w_hh1,
               const float* __restrict__ b_ih1,
               const float* __restrict__ b_hh1,
               const float* __restrict__ w_ih2,
               const float* __restrict__ w_hh2,
               const float* __restrict__ b_ih2,
               const float* __restrict__ b_hh2,
               const float* __restrict__ w_lin,
               const float* __restrict__ b_lin,
               float* __restrict__ out,
               char* __restrict__ ws,
               int T, int F, int S)
{
    const int tid = threadIdx.x;
    unsigned* a_prog  = (unsigned*)(ws + OFF_APROG);
    unsigned* p2_prog = (unsigned*)(ws + OFF_P2PROG);
    unsigned* b_prog  = (unsigned*)(ws + OFF_BPROG);
    float* ring1 = (float*)(ws + OFF_RING);
    float* ring2 = ring1 + (size_t)S * HH;
    const int smask = S - 1;
    const int TOT = T + F;

    if (blockIdx.x == 0) {
        // ======== A-group (layer 1) + B-group (layer 2 + output), one CU ========
        __shared__ __align__(16) float h1s[2][128];
        __shared__ __align__(16) float h2s[2][128];
        __shared__ float ypart[2][4];
        __shared__ float yring[16];
        __shared__ unsigned aarr[4], barr[4], darr[4];
        __shared__ unsigned yflag;

        const int a = tid & 255;          // group-local id
        const int l = a & 63;
        const int w = a >> 6;             // wave within group
        const bool isA = (tid < 256);
        // wave w owns cells 25w..25w+24; lanes 0-24: (i,f) rows; 32-56: (g,o).
        const bool gi_lane = (l < 25);
        const bool go_lane = (l >= 32 && l < 57);
        const int cell = 25 * w + (gi_lane ? l : (go_lane ? (l - 32) : 0));
        const int gj0 = gi_lane ? cell : (go_lane ? cell + 200 : 0);
        const int gj1 = gi_lane ? cell + 100 : (go_lane ? cell + 300 : 0);

        if (tid < 4) { aarr[tid] = 0; barr[tid] = 0; darr[tid] = 0; }
        if (tid == 4) yflag = 0;
        if (tid < 128) { h1s[0][tid] = (tid < HH) ? enc_h[tid] : 0.f; h1s[1][tid] = 0.f; }
        else if (tid < 256) { int q = tid - 128; h2s[0][q] = 0.f; h2s[1][q] = 0.f; }

        float w0[HH], w1[HH];
        float wx0 = 0.f, wx1 = 0.f, bi0 = 0.f, bi1 = 0.f, wl = 0.f, cst = 0.f;
        const float bl = b_lin[0];
        if (isA) {
            wx0 = w_ih1[gj0]; wx1 = w_ih1[gj1];
            bi0 = b_ih1[gj0] + b_hh1[gj0];
            bi1 = b_ih1[gj1] + b_hh1[gj1];
            #pragma unroll
            for (int k = 0; k < HH; ++k) w0[k] = w_hh1[gj0 * HH + k];
            #pragma unroll
            for (int k = 0; k < HH; ++k) w1[k] = w_hh1[gj1 * HH + k];
            cst = gi_lane ? enc_c[cell] : 0.f;
        } else {
            #pragma unroll
            for (int k = 0; k < HH; ++k) w0[k] = w_hh2[gj0 * HH + k];
            #pragma unroll
            for (int k = 0; k < HH; ++k) w1[k] = w_hh2[gj1 * HH + k];
            wl = gi_lane ? w_lin[cell] : 0.f;
        }
        __syncthreads();   // the ONLY block-wide barrier (publishes LDS init)

        if (isA) {
            // ---------------- A: layer-1 recurrence ----------------
            unsigned cp2 = 0;
            for (int t = 0; t < TOT; ++t) {
                // certify step t-1's ring1 stores (vmcnt drain hidden: ack landed
                // under previous iteration) and publish a_prog = t.
                fence_rel_agent();
                if (l == 0) st_lds(&darr[w], (unsigned)t);
                if (tid == 0) {
                    spin_min4(darr, (unsigned)t);
                    if (t > 0) rel(a_prog, (unsigned)t);
                }
                float xld = 0.f;
                if (t < T) xld = input[t];
                if (t >= S) wait_ge(p2_prog, (unsigned)(t - S + 1), cp2);  // ring1 guard
                float hv0 = h1s[t & 1][l];
                float hv1 = h1s[t & 1][64 + l];
                float accA = bi0, accB = bi1;
                dot2rows(w0, w1, hv0, hv1, accA, accB);
                float x = xld;
                if (t >= T) {            // future: dot done, now wait for y(t-1) via LDS
                    unsigned s = 0;
                    while (__hip_atomic_load(&yflag, __ATOMIC_ACQUIRE,
                                             __HIP_MEMORY_SCOPE_WORKGROUP) < (unsigned)t)
                        if (++s > SPIN_CAP) break;
                    x = yring[(t - 1) & 15];
                }
                accA = fmaf(x, wx0, accA);
                accB = fmaf(x, wx1, accB);
                float vA = go_lane ? fast_tanh(accA) : fast_sigm(accA);  // i or g
                float vB = fast_sigm(accB);                              // f or o
                float gg = __shfl_xor(vA, 32);
                float go = __shfl_xor(vB, 32);
                if (gi_lane) {
                    cst = fmaf(vB, cst, vA * gg);
                    float h = go * fast_tanh(cst);
                    h1s[(t + 1) & 1][cell] = h;
                    st_wt(&ring1[(size_t)(t & smask) * HH + cell], h);
                }
                grp_barrier(aarr, w, l, (unsigned)(t + 1));   // h1 exchange
            }
            // final certify + release
            fence_rel_agent();
            if (l == 0) st_lds(&darr[w], (unsigned)TOT);
            if (tid == 0) { spin_min4(darr, (unsigned)TOT); rel(a_prog, (unsigned)TOT); }
        } else {
            // ---------------- B: layer-2 recurrence + output ----------------
            unsigned cpB = 0;
            for (int u = 0; u < TOT; ++u) {
                float hv0 = h2s[u & 1][l];
                float hv1 = h2s[u & 1][64 + l];
                float accA = 0.f, accB = 0.f, preA, preB;
                if (u < T) {             // encode: wait first, loads hide under dot
                    wait_ge(p2_prog, (unsigned)(u + 1), cpB);
                    const float* pp = ring2 + (size_t)(u & smask) * ROWS;
                    preA = ld_f(pp + gj0);
                    preB = ld_f(pp + gj1);
                    dot2rows(w0, w1, hv0, hv1, accA, accB);
                } else {                 // future: local dot first, then wait
                    dot2rows(w0, w1, hv0, hv1, accA, accB);
                    wait_ge(p2_prog, (unsigned)(u + 1), cpB);
                    const float* pp = ring2 + (size_t)(u & smask) * ROWS;
                    preA = ld_f(pp + gj0);
                    preB = ld_f(pp + gj1);
                }
                accA += preA; accB += preB;
                float vA = go_lane ? fast_tanh(accA) : fast_sigm(accA);
                float vB = fast_sigm(accB);
                float gg = __shfl_xor(vA, 32);
                float go = __shfl_xor(vB, 32);
                float py = 0.f;
                if (gi_lane) {
                    cst = fmaf(vB, cst, vA * gg);
                    float h = go * fast_tanh(cst);
                    h2s[(u + 1) & 1][cell] = h;
                    py = h * wl;
                }
                py += __shfl_down(py, 32);
                py += __shfl_down(py, 16);
                py += __shfl_down(py, 8);
                py += __shfl_down(py, 4);
                py += __shfl_down(py, 2);
                py += __shfl_down(py, 1);
                if (l == 0) ypart[u & 1][w] = py;
                grp_barrier(barr, w, l, (unsigned)(u + 1));   // h2 + ypart exchange
                if (a == 0) {
                    const float* yq = ypart[u & 1];
                    float y = yq[0] + yq[1] + yq[2] + yq[3] + bl;
                    out[u] = y;
                    yring[u & 15] = y;
                    __hip_atomic_store(&yflag, (unsigned)(u + 1), __ATOMIC_RELEASE,
                                       __HIP_MEMORY_SCOPE_WORKGROUP);
                    rel(b_prog, (unsigned)(u + 1));   // ring2 slot u consumed
                }
            }
        }
    } else {
        // ================= A2: pre2 = w_ih2*h1 + biases =================
        __shared__ unsigned carr[4];
        if (tid < 4) carr[tid] = 0;
        __syncthreads();                  // before idle waves exit
        if (tid >= 256) return;           // waves 4-7 idle; no barriers follow

        const bool has2 = tid < (ROWS - 256);   // tid < 144 owns a second row
        const int j0 = tid, j1 = has2 ? 256 + tid : 0;
        const int l = tid & 63;
        const int w = tid >> 6;
        float w0[HH], w1[HH];
        const float bi0 = b_ih2[j0] + b_hh2[j0];
        const float bi1 = b_ih2[j1] + b_hh2[j1];
        #pragma unroll
        for (int k = 0; k < HH; ++k) w0[k] = w_ih2[j0 * HH + k];
        #pragma unroll
        for (int k = 0; k < HH; ++k) w1[k] = w_ih2[j1 * HH + k];

        unsigned ca = 0, cb = 0;
        for (int t = 0; t < TOT; ++t) {
            // certify step t-1's ring2 stores, publish p2_prog = t (early fence)
            fence_rel_agent();
            if (l == 0) st_lds(&carr[w], (unsigned)t);
            if (tid == 0) {
                spin_min4(carr, (unsigned)t);
                if (t > 0) rel(p2_prog, (unsigned)t);
            }
            if (t >= S) wait_ge(b_prog, (unsigned)(t - S + 1), cb);  // ring2 guard
            wait_ge(a_prog, (unsigned)(t + 1), ca);
            const float* rp = ring1 + (size_t)(t & smask) * HH;
            float hv0 = ld_f(rp + l);
            float hv1 = (l < 36) ? ld_f(rp + 64 + l) : 0.f;
            float accA = bi0, accB = bi1;
            dot2rows(w0, w1, hv0, hv1, accA, accB);
            float* wp = ring2 + (size_t)(t & smask) * ROWS;
            st_wt(&wp[j0], accA);
            if (has2) st_wt(&wp[j1], accB);
        }
        fence_rel_agent();
        if (l == 0) st_lds(&carr[w], (unsigned)TOT);
        if (tid == 0) { spin_min4(carr, (unsigned)TOT); rel(p2_prog, (unsigned)TOT); }
    }
}

extern "C" void kernel_launch(void* const* d_in, const int* in_sizes, int n_in,
                              void* d_out, int out_size, void* d_ws, size_t ws_size,
                              hipStream_t stream) {
    const float* input = (const float*)d_in[0];
    const float* enc_h = (const float*)d_in[1];
    const float* enc_c = (const float*)d_in[2];
    const float* w_ih1 = (const float*)d_in[3];
    const float* w_hh1 = (const float*)d_in[4];
    const float* b_ih1 = (const float*)d_in[5];
    const float* b_hh1 = (const float*)d_in[6];
    const float* w_ih2 = (const float*)d_in[7];
    const float* w_hh2 = (const float*)d_in[8];
    const float* b_ih2 = (const float*)d_in[9];
    const float* b_hh2 = (const float*)d_in[10];
    const float* w_lin = (const float*)d_in[11];
    const float* b_lin = (const float*)d_in[12];
    (void)n_in;

    int T = in_sizes[0];
    int F = out_size - T;
    if (F < 0) F = 0;

    // largest power-of-two ring slot count that fits both rings in d_ws
    int S = 16;
    while ((size_t)OFF_RING + (size_t)S * 2 * (HH + ROWS) * 4 <= ws_size && S < 8192)
        S <<= 1;

    decoder_kernel<<<dim3(2), dim3(NT), 0, stream>>>(
        input, enc_h, enc_c, w_ih1, w_hh1, b_ih1, b_hh1,
        w_ih2, w_hh2, b_ih2, b_hh2, w_lin, b_lin,
        (float*)d_out, (char*)d_ws, T, F, S);
}

// Round 3
// 16702.251 us; speedup vs baseline: 4.3194x; 4.3194x over previous
//
#include <hip/hip_runtime.h>
#include <math.h>

// 2-layer LSTM decoder, H=100, T=8192 encode + F=1024 future steps, fp32.
// Three persistent blocks (3 CUs), 256 threads (4 waves) each:
//   block 0 (A) : layer-1 recurrence. gates1 = w_ih1*x + w_hh1*h1 + b. h1 -> ring1.
//   block 1 (A2): feed-forward pre2 = w_ih2*h1 + biases. ring1 -> ring2.
//                 4 INDEPENDENT waves, no barriers, 1-deep load pipeline.
//   block 2 (B) : layer-2 recurrence gates2 = pre2 + w_hh2*h2; y = h2.w_lin + b.
//
// V3 sync design (no bulk-L2 ops anywhere in the hot loop):
//  * All cross-CU data uses relaxed agent atomics (sc1, LLC-direct). Ordering is
//    done purely with s_waitcnt vmcnt: producer waits own store acks before the
//    flag store; consumer orders data loads after flag observation. NO
//    __builtin_amdgcn_fence (agent fences emit buffer_wbl2/buffer_inv = whole-L2
//    walks; V2 showed these double WRITE_SIZE and collapse throughput).
//  * Per-wave progress flags aw[4] (A) / p2w[4] (A2); consumers take min of 4.
//    Producers publish at the TOP of the next iteration, after the store has
//    aged a full iteration -> the certifying vmcnt wait is nearly free. The
//    publish precedes all blocking waits, so the future-phase serial chain
//    y->A->A2->B never waits on a publish (no deadlock).
//  * A and B use raw s_barrier + lgkmcnt(0) (LDS-only drain) instead of
//    __syncthreads (which drains vmcnt(0) and re-exposes ring-store acks).
//  * A2 encode is software-pipelined (prefetch ring1[t] under the dot of
//    h(t-1)); certification via counted s_waitcnt vmcnt(2) (vmcnt retires in
//    issue order, so <=2 outstanding proves everything older is acked).
//    Future phase switches to straight mode (serial chain needs same-step data).
//  * Flags monotone <= 9217, so 0xAA workspace poison sanitizes to 0.

#define HH 100
#define NT 256
#define ROWS 400
#define SPIN_CAP 2000000u

#define OFF_AW     0       // unsigned aw[4]  : A per-wave publish counters
#define OFF_P2W    128     // unsigned p2w[4] : A2 per-wave publish counters
#define OFF_BPROG  256     // unsigned        : B consumption counter
#define OFF_YPROG  384     // unsigned        : y produced counter
#define OFF_YSLOT  512     // float[F+1]
#define OFF_RING   16384

#define VMCNT0() asm volatile("s_waitcnt vmcnt(0)" ::: "memory")
#define VMCNT2() asm volatile("s_waitcnt vmcnt(2)" ::: "memory")
#define LGKM0()  asm volatile("s_waitcnt lgkmcnt(0)" ::: "memory")
#define CLOB()   asm volatile("" ::: "memory")

__device__ __forceinline__ float rl(float v, int k) {
    return __int_as_float(__builtin_amdgcn_readlane(__float_as_int(v), k));
}
__device__ __forceinline__ unsigned san(unsigned v) { return v > 0x00FFFFFFu ? 0u : v; }
__device__ __forceinline__ unsigned ldu(const unsigned* p) {
    return san(__hip_atomic_load((unsigned*)p, __ATOMIC_RELAXED, __HIP_MEMORY_SCOPE_AGENT));
}
__device__ __forceinline__ void stu(unsigned* p, unsigned v) {
    __hip_atomic_store(p, v, __ATOMIC_RELAXED, __HIP_MEMORY_SCOPE_AGENT);
}
__device__ __forceinline__ float ld_f(const float* p) {
    return __hip_atomic_load((float*)p, __ATOMIC_RELAXED, __HIP_MEMORY_SCOPE_AGENT);
}
__device__ __forceinline__ void st_wt(float* p, float v) {
    __hip_atomic_store(p, v, __ATOMIC_RELAXED, __HIP_MEMORY_SCOPE_AGENT);
}
// Cached waits: poll relaxed; order subsequent data loads with vmcnt(0) only.
__device__ __forceinline__ void wait_ge(unsigned* p, unsigned need, unsigned& cache) {
    if (cache >= need) return;
    unsigned s = 0;
    do { cache = ldu(p); } while (cache < need && ++s < SPIN_CAP);
    VMCNT0();
}
__device__ __forceinline__ void wait_min4(unsigned* q, unsigned need, unsigned& cache) {
    if (cache >= need) return;
    unsigned s = 0;
    for (;;) {
        unsigned m0 = ldu(q), m1 = ldu(q + 1), m2 = ldu(q + 2), m3 = ldu(q + 3);
        unsigned a = m0 < m1 ? m0 : m1, b = m2 < m3 ? m2 : m3;
        cache = a < b ? a : b;
        if (cache >= need || ++s > SPIN_CAP) break;
    }
    VMCNT0();
}
// Raw workgroup barrier: LDS drain only (no vmcnt -> ring stores stay in flight).
__device__ __forceinline__ void bar() {
    LGKM0();
    __builtin_amdgcn_s_barrier();
    CLOB();
}
__device__ __forceinline__ float fast_sigm(float x) {
    return __builtin_amdgcn_rcpf(1.0f + __expf(-x));
}
__device__ __forceinline__ float fast_tanh(float x) {
    return fmaf(-2.0f, __builtin_amdgcn_rcpf(1.0f + __expf(2.0f * x)), 1.0f);
}

// accA += dot(w0, h), accB += dot(w1, h); h lane-indexed: hv0 lane k = h[k],
// hv1 lane k = h[64+k] (k<36).
__device__ __forceinline__ void dot2rows(const float* w0, const float* w1,
                                         float hv0, float hv1,
                                         float& accA, float& accB) {
    float a0 = 0.f, a1 = 0.f, b0 = 0.f, b1 = 0.f;
    #pragma unroll
    for (int k = 0; k < 64; k += 2) {
        float h0 = rl(hv0, k), h1 = rl(hv0, k + 1);
        a0 = fmaf(w0[k],     h0, a0);
        a1 = fmaf(w0[k + 1], h1, a1);
        b0 = fmaf(w1[k],     h0, b0);
        b1 = fmaf(w1[k + 1], h1, b1);
    }
    #pragma unroll
    for (int k = 0; k < 36; k += 2) {
        float h0 = rl(hv1, k), h1 = rl(hv1, k + 1);
        a0 = fmaf(w0[64 + k],     h0, a0);
        a1 = fmaf(w0[64 + k + 1], h1, a1);
        b0 = fmaf(w1[64 + k],     h0, b0);
        b1 = fmaf(w1[64 + k + 1], h1, b1);
    }
    accA += (a0 + a1);
    accB += (b0 + b1);
}

extern "C" __global__ void __launch_bounds__(NT, 1)
decoder_kernel(const float* __restrict__ input,
               const float* __restrict__ enc_h,
               const float* __restrict__ enc_c,
               const float* __restrict__ w_ih1,
               const float* __restrict__ w_hh1,
               const float* __restrict__ b_ih1,
               const float* __restrict__ b_hh1,
               const float* __restrict__ w_ih2,
               const float* __restrict__ w_hh2,
               const float* __restrict__ b_ih2,
               const float* __restrict__ b_hh2,
               const float* __restrict__ w_lin,
               const float* __restrict__ b_lin,
               float* __restrict__ out,
               char* __restrict__ ws,
               int T, int F, int S)
{
    const int tid = threadIdx.x;
    const int l = tid & 63;
    const int w = tid >> 6;
    unsigned* aw     = (unsigned*)(ws + OFF_AW);
    unsigned* p2w    = (unsigned*)(ws + OFF_P2W);
    unsigned* b_prog = (unsigned*)(ws + OFF_BPROG);
    unsigned* y_prog = (unsigned*)(ws + OFF_YPROG);
    float* y_slot = (float*)(ws + OFF_YSLOT);
    float* ring1  = (float*)(ws + OFF_RING);
    float* ring2  = ring1 + (size_t)S * HH;
    const int smask = S - 1;
    const int TOT = T + F;

    // Gate lane mapping (blocks A and B): wave w owns cells 25w..25w+24.
    // lanes 0-24: rows cell (i), cell+100 (f); lanes 32-56: cell+200 (g), cell+300 (o).
    const bool gi_lane = (l < 25);
    const bool go_lane = (l >= 32 && l < 57);
    const int cell = 25 * w + (gi_lane ? l : (go_lane ? (l - 32) : 0));
    const int gj0 = gi_lane ? cell : (go_lane ? cell + 200 : 0);
    const int gj1 = gi_lane ? cell + 100 : (go_lane ? cell + 300 : 0);

    if (blockIdx.x == 0) {
        // ================= A: layer-1 recurrence =================
        __shared__ __align__(16) float h1s[2][128];
        float w0[HH], w1[HH];
        const float wx0 = w_ih1[gj0];
        const float wx1 = w_ih1[gj1];
        const float bi0 = b_ih1[gj0] + b_hh1[gj0];
        const float bi1 = b_ih1[gj1] + b_hh1[gj1];
        #pragma unroll
        for (int k = 0; k < HH; ++k) w0[k] = w_hh1[gj0 * HH + k];
        #pragma unroll
        for (int k = 0; k < HH; ++k) w1[k] = w_hh1[gj1 * HH + k];
        float cst = gi_lane ? enc_c[cell] : 0.f;
        if (tid < 128) {
            h1s[0][tid] = (tid < HH) ? enc_h[tid] : 0.f;
            h1s[1][tid] = 0.f;
        }
        __syncthreads();

        unsigned cp2 = 0, cy = 0;
        for (int t = 0; t < TOT; ++t) {
            // publish slot t-1: ring1 stores aged ~1 iteration -> vmcnt(0) cheap.
            VMCNT0();
            if (l == 0 && t > 0) stu(&aw[w], (unsigned)t);     // slots <= t-1 valid
            float x = 0.f;
            if (t < T) x = input[t];
            // ring1 overwrite guard: A2 consumed slot t-S when min(p2w) >= t-S+1
            if (t >= S) wait_min4(p2w, (unsigned)(t - S + 1), cp2);
            float hv0 = h1s[t & 1][l];
            float hv1 = h1s[t & 1][64 + l];    // lanes >=36 hold 0, never readlaned
            float accA = bi0, accB = bi1;
            dot2rows(w0, w1, hv0, hv1, accA, accB);
            if (t >= T) {                       // future: dot done, now wait for y
                wait_ge(y_prog, (unsigned)(t - T + 1), cy);
                x = ld_f(&y_slot[t - T]);
            }
            accA = fmaf(x, wx0, accA);
            accB = fmaf(x, wx1, accB);
            float vA = go_lane ? fast_tanh(accA) : fast_sigm(accA);  // i or g
            float vB = fast_sigm(accB);                              // f or o
            float gg = __shfl_xor(vA, 32);
            float go = __shfl_xor(vB, 32);
            if (gi_lane) {
                cst = fmaf(vB, cst, vA * gg);
                float h = go * fast_tanh(cst);
                h1s[(t + 1) & 1][cell] = h;
                st_wt(&ring1[(size_t)(t & smask) * HH + cell], h);
            }
            bar();    // LDS-only drain; ring1 stores stay in flight across it
        }
        VMCNT0();
        if (l == 0) stu(&aw[w], (unsigned)TOT);
    } else if (blockIdx.x == 1) {
        // ===== A2: pre2 = w_ih2*h1 + biases. 4 independent waves, no barriers. =====
        const bool has2 = tid < (ROWS - NT);   // tid < 144 owns a second row
        const int j0 = tid, j1 = has2 ? NT + tid : 0;
        float w0[HH], w1[HH];
        const float bi0 = b_ih2[j0] + b_hh2[j0];
        const float bi1 = b_ih2[j1] + b_hh2[j1];
        #pragma unroll
        for (int k = 0; k < HH; ++k) w0[k] = w_ih2[j0 * HH + k];
        #pragma unroll
        for (int k = 0; k < HH; ++k) w1[k] = w_ih2[j1 * HH + k];

        unsigned ca = 0, cb = 0;
        // ---- prologue: load slot 0
        wait_min4(aw, 1u, ca);
        float cv0 = ld_f(ring1 + l);
        float cv1 = (l < 36) ? ld_f(ring1 + 64 + l) : 0.f;
        // ---- pipelined encode: iter t stores slot t-1, prefetches slot t.
        // Counted vmcnt(2): vmcnt retires in issue order, so <=2 outstanding
        // proves all stores up to slot t-3 are acked -> publish p2w = t-2.
        for (int t = 1; t < T; ++t) {
            VMCNT2();
            if (l == 0 && t >= 3) stu(&p2w[w], (unsigned)(t - 2));  // slots <= t-3 valid
            if (t - 1 >= S) wait_ge(b_prog, (unsigned)(t - S), cb); // overwrite guard
            wait_min4(aw, (unsigned)(t + 1), ca);                   // slot t readable
            const float* rp = ring1 + (size_t)(t & smask) * HH;
            float nv0 = ld_f(rp + l);
            float nv1 = (l < 36) ? ld_f(rp + 64 + l) : 0.f;
            float accA = bi0, accB = bi1;
            dot2rows(w0, w1, cv0, cv1, accA, accB);                 // h(t-1)
            float* wp = ring2 + (size_t)((t - 1) & smask) * ROWS;
            st_wt(wp + j0, accA);
            if (has2) st_wt(wp + j1, accB);
            cv0 = nv0; cv1 = nv1;
        }
        // ---- boundary: drain pipeline, then slot T-1 straight.
        VMCNT0();
        if (l == 0) stu(&p2w[w], (unsigned)(T - 1));                // slots <= T-2 valid
        {
            if (T - 1 >= S) wait_ge(b_prog, (unsigned)(T - S), cb);
            float accA = bi0, accB = bi1;
            dot2rows(w0, w1, cv0, cv1, accA, accB);                 // h(T-1)
            float* wp = ring2 + (size_t)((T - 1) & smask) * ROWS;
            st_wt(wp + j0, accA);
            if (has2) st_wt(wp + j1, accB);
        }
        VMCNT0();
        if (l == 0) stu(&p2w[w], (unsigned)T);                      // slots <= T-1 valid
        // ---- future: straight mode (serial chain needs same-step data).
        for (int t = T; t < TOT; ++t) {
            if (t >= S) wait_ge(b_prog, (unsigned)(t - S + 1), cb);
            wait_min4(aw, (unsigned)(t + 1), ca);
            const float* rp = ring1 + (size_t)(t & smask) * HH;
            cv0 = ld_f(rp + l);
            cv1 = (l < 36) ? ld_f(rp + 64 + l) : 0.f;
            float accA = bi0, accB = bi1;
            dot2rows(w0, w1, cv0, cv1, accA, accB);
            float* wp = ring2 + (size_t)(t & smask) * ROWS;
            st_wt(wp + j0, accA);
            if (has2) st_wt(wp + j1, accB);
            VMCNT0();
            if (l == 0) stu(&p2w[w], (unsigned)(t + 1));
        }
    } else {
        // ================= B: layer-2 recurrence + output =================
        __shared__ __align__(16) float h2s[2][128];
        __shared__ float yp2[2][4];
        float w0[HH], w1[HH];
        #pragma unroll
        for (int k = 0; k < HH; ++k) w0[k] = w_hh2[gj0 * HH + k];
        #pragma unroll
        for (int k = 0; k < HH; ++k) w1[k] = w_hh2[gj1 * HH + k];
        const float wl = gi_lane ? w_lin[cell] : 0.f;
        const float bl = b_lin[0];
        float c2 = 0.f;
        if (tid < 128) { h2s[0][tid] = 0.f; h2s[1][tid] = 0.f; }
        __syncthreads();

        unsigned cpB = 0;
        for (int u = 0; u < TOT; ++u) {
            // Emit previous step's y right after its barrier.
            if (tid == 0 && u > 0) {
                const float* yq = yp2[(u - 1) & 1];
                float y = yq[0] + yq[1] + yq[2] + yq[3] + bl;
                stu(b_prog, (unsigned)u);        // consumed ring2 slot u-1 (loads retired pre-barrier)
                if (u - 1 >= T - 1) {
                    st_wt(&y_slot[(u - 1) - (T - 1)], y);
                    VMCNT0();                    // y_slot store acked before flag
                    stu(y_prog, (unsigned)(u - T + 1));
                }
                out[u - 1] = y;
            }
            float hv0 = h2s[u & 1][l];
            float hv1 = h2s[u & 1][64 + l];
            const float* pp = ring2 + (size_t)(u & smask) * ROWS;
            float accA = 0.f, accB = 0.f, preA, preB;
            if (u < T) {     // encode: wait first so pre2 load latency hides under dot
                wait_min4(p2w, (unsigned)(u + 1), cpB);
                preA = ld_f(pp + gj0);
                preB = ld_f(pp + gj1);
                dot2rows(w0, w1, hv0, hv1, accA, accB);
            } else {         // future: local dot first, then wait
                dot2rows(w0, w1, hv0, hv1, accA, accB);
                wait_min4(p2w, (unsigned)(u + 1), cpB);
                preA = ld_f(pp + gj0);
                preB = ld_f(pp + gj1);
            }
            accA += preA; accB += preB;
            float vA = go_lane ? fast_tanh(accA) : fast_sigm(accA);
            float vB = fast_sigm(accB);
            float gg = __shfl_xor(vA, 32);
            float go = __shfl_xor(vB, 32);
            float py = 0.f;
            if (gi_lane) {
                c2 = fmaf(vB, c2, vA * gg);
                float h = go * fast_tanh(c2);
                h2s[(u + 1) & 1][cell] = h;
                py = h * wl;
            }
            py += __shfl_down(py, 32);
            py += __shfl_down(py, 16);
            py += __shfl_down(py, 8);
            py += __shfl_down(py, 4);
            py += __shfl_down(py, 2);
            py += __shfl_down(py, 1);
            if (l == 0) yp2[u & 1][w] = py;
            bar();
        }
        if (tid == 0) {   // final step's y
            const float* yq = yp2[(TOT - 1) & 1];
            out[TOT - 1] = yq[0] + yq[1] + yq[2] + yq[3] + bl;
        }
    }
}

extern "C" void kernel_launch(void* const* d_in, const int* in_sizes, int n_in,
                              void* d_out, int out_size, void* d_ws, size_t ws_size,
                              hipStream_t stream) {
    const float* input = (const float*)d_in[0];
    const float* enc_h = (const float*)d_in[1];
    const float* enc_c = (const float*)d_in[2];
    const float* w_ih1 = (const float*)d_in[3];
    const float* w_hh1 = (const float*)d_in[4];
    const float* b_ih1 = (const float*)d_in[5];
    const float* b_hh1 = (const float*)d_in[6];
    const float* w_ih2 = (const float*)d_in[7];
    const float* w_hh2 = (const float*)d_in[8];
    const float* b_ih2 = (const float*)d_in[9];
    const float* b_hh2 = (const float*)d_in[10];
    const float* w_lin = (const float*)d_in[11];
    const float* b_lin = (const float*)d_in[12];
    (void)n_in;

    int T = in_sizes[0];
    int F = out_size - T;
    if (F < 0) F = 0;

    // largest power-of-two ring slot count that fits both rings in d_ws
    int S = 16;
    while ((size_t)OFF_RING + (size_t)S * 2 * (HH + ROWS) * 4 <= ws_size && S < 8192)
        S <<= 1;

    decoder_kernel<<<dim3(3), dim3(NT), 0, stream>>>(
        input, enc_h, enc_c, w_ih1, w_hh1, b_ih1, b_hh1,
        w_ih2, w_hh2, b_ih2, b_hh2, w_lin, b_lin,
        (float*)d_out, (char*)d_ws, T, F, S);
}

// Round 4
// 16198.924 us; speedup vs baseline: 4.4536x; 1.0311x over previous
//
#include <hip/hip_runtime.h>
#include <math.h>

// 2-layer LSTM decoder, H=100, T=8192 encode + F=1024 future steps, fp32.
// Three persistent blocks (3 CUs), 256 threads (4 waves) each:
//   block 0 (A) : layer-1 recurrence. gates1 = w_ih1*x + w_hh1*h1 + b. h1 -> ring1.
//   block 1 (A2): feed-forward pre2 = w_ih2*h1 + biases. ring1 -> ring2.
//                 4 INDEPENDENT waves, no barriers, 1-deep load pipeline.
//   block 2 (B) : layer-2 recurrence gates2 = pre2 + w_hh2*h2; y = h2.w_lin + b.
//
// V4: weights FORCED into VGPRs. V3 showed VGPR_Count=124 with 200 floats of
// per-thread weights declared as float w0[100],w1[100] -> the compiler never
// promoted the arrays; every iteration re-streamed ~800B/thread of weights
// from cache (the real bottleneck; all stages were L1/L2-BW-bound, not
// sync-bound). Fix: 50 NAMED float4 locals per thread (macro-generated) with
// all-compile-time indexing -> mem2reg promotes unconditionally. Expect
// VGPR_Count ~260 (the certificate), dot becomes issue-bound (~600cy).
//
// Sync design (unchanged from V3, proven correct):
//  * Cross-CU data via relaxed agent atomics; ordering via s_waitcnt vmcnt only
//    (producer: vmcnt(0) before flag store; consumer: vmcnt(0) after flag obs).
//    NO agent fences (they emit whole-L2 buffer_wbl2/inv - V2 regression).
//  * Per-wave progress flags aw[4]/p2w[4], consumer takes min4; producers
//    publish at top-of-next-iteration (store acks aged ~1 iter -> vmcnt free).
//  * A/B use raw s_barrier + lgkmcnt(0) (LDS-only drain, ring stores stay in
//    flight). A2: counted vmcnt(2) certify, 1-deep prefetch pipeline in encode,
//    straight mode in future.
//  * Flags monotone <= 9217 -> 0xAA workspace poison sanitizes to 0.

#define HH 100
#define NT 256
#define ROWS 400
#define SPIN_CAP 2000000u

#define OFF_AW     0       // unsigned aw[4]  : A per-wave publish counters
#define OFF_P2W    128     // unsigned p2w[4] : A2 per-wave publish counters
#define OFF_BPROG  256     // unsigned        : B consumption counter
#define OFF_YPROG  384     // unsigned        : y produced counter
#define OFF_YSLOT  512     // float[F+1]
#define OFF_RING   16384

#define VMCNT0() asm volatile("s_waitcnt vmcnt(0)" ::: "memory")
#define VMCNT2() asm volatile("s_waitcnt vmcnt(2)" ::: "memory")
#define LGKM0()  asm volatile("s_waitcnt lgkmcnt(0)" ::: "memory")
#define CLOB()   asm volatile("" ::: "memory")

__device__ __forceinline__ float rl(float v, int k) {
    return __int_as_float(__builtin_amdgcn_readlane(__float_as_int(v), k));
}
__device__ __forceinline__ unsigned san(unsigned v) { return v > 0x00FFFFFFu ? 0u : v; }
__device__ __forceinline__ unsigned ldu(const unsigned* p) {
    return san(__hip_atomic_load((unsigned*)p, __ATOMIC_RELAXED, __HIP_MEMORY_SCOPE_AGENT));
}
__device__ __forceinline__ void stu(unsigned* p, unsigned v) {
    __hip_atomic_store(p, v, __ATOMIC_RELAXED, __HIP_MEMORY_SCOPE_AGENT);
}
__device__ __forceinline__ float ld_f(const float* p) {
    return __hip_atomic_load((float*)p, __ATOMIC_RELAXED, __HIP_MEMORY_SCOPE_AGENT);
}
__device__ __forceinline__ void st_wt(float* p, float v) {
    __hip_atomic_store(p, v, __ATOMIC_RELAXED, __HIP_MEMORY_SCOPE_AGENT);
}
__device__ __forceinline__ void wait_ge(unsigned* p, unsigned need, unsigned& cache) {
    if (cache >= need) return;
    unsigned s = 0;
    do { cache = ldu(p); } while (cache < need && ++s < SPIN_CAP);
    VMCNT0();
}
__device__ __forceinline__ void wait_min4(unsigned* q, unsigned need, unsigned& cache) {
    if (cache >= need) return;
    unsigned s = 0;
    for (;;) {
        unsigned m0 = ldu(q), m1 = ldu(q + 1), m2 = ldu(q + 2), m3 = ldu(q + 3);
        unsigned a = m0 < m1 ? m0 : m1, b = m2 < m3 ? m2 : m3;
        cache = a < b ? a : b;
        if (cache >= need || ++s > SPIN_CAP) break;
    }
    VMCNT0();
}
// Raw workgroup barrier: LDS drain only (ring stores stay in flight).
__device__ __forceinline__ void bar() {
    LGKM0();
    __builtin_amdgcn_s_barrier();
    CLOB();
}
__device__ __forceinline__ float fast_sigm(float x) {
    return __builtin_amdgcn_rcpf(1.0f + __expf(-x));
}
__device__ __forceinline__ float fast_tanh(float x) {
    return fmaf(-2.0f, __builtin_amdgcn_rcpf(1.0f + __expf(2.0f * x)), 1.0f);
}

// ---- weight registers: 25 chunks x float4 x 2 rows, all NAMED locals ----
#define REP25(M) M(0) M(1) M(2) M(3) M(4) M(5) M(6) M(7) M(8) M(9) M(10) M(11) \
                 M(12) M(13) M(14) M(15) M(16) M(17) M(18) M(19) M(20) M(21) M(22) M(23) M(24)
#define DECLW(i) float4 W0_##i, W1_##i;
#define LOADW(i) W0_##i = r0p[i]; W1_##i = r1p[i];
// chunk i covers h[4i..4i+3]; i<16 from hv0 (lanes 4i..), i>=16 from hv1 (lanes 4(i-16)..)
#define DOTC(i) { \
    const float hsv = ((i) < 16) ? hv0 : hv1; \
    const int kb = ((i) < 16) ? (4 * (i)) : (4 * ((i) - 16)); \
    float h0 = rl(hsv, kb), h1 = rl(hsv, kb + 1), h2 = rl(hsv, kb + 2), h3 = rl(hsv, kb + 3); \
    a0 = fmaf(W0_##i.x, h0, a0); b0 = fmaf(W1_##i.x, h0, b0); \
    a1 = fmaf(W0_##i.y, h1, a1); b1 = fmaf(W1_##i.y, h1, b1); \
    a0 = fmaf(W0_##i.z, h2, a0); b0 = fmaf(W1_##i.z, h2, b0); \
    a1 = fmaf(W0_##i.w, h3, a1); b1 = fmaf(W1_##i.w, h3, b1); \
}

extern "C" __global__ void __launch_bounds__(NT, 1)
decoder_kernel(const float* __restrict__ input,
               const float* __restrict__ enc_h,
               const float* __restrict__ enc_c,
               const float* __restrict__ w_ih1,
               const float* __restrict__ w_hh1,
               const float* __restrict__ b_ih1,
               const float* __restrict__ b_hh1,
               const float* __restrict__ w_ih2,
               const float* __restrict__ w_hh2,
               const float* __restrict__ b_ih2,
               const float* __restrict__ b_hh2,
               const float* __restrict__ w_lin,
               const float* __restrict__ b_lin,
               float* __restrict__ out,
               char* __restrict__ ws,
               int T, int F, int S)
{
    const int tid = threadIdx.x;
    const int l = tid & 63;
    const int w = tid >> 6;
    unsigned* aw     = (unsigned*)(ws + OFF_AW);
    unsigned* p2w    = (unsigned*)(ws + OFF_P2W);
    unsigned* b_prog = (unsigned*)(ws + OFF_BPROG);
    unsigned* y_prog = (unsigned*)(ws + OFF_YPROG);
    float* y_slot = (float*)(ws + OFF_YSLOT);
    float* ring1  = (float*)(ws + OFF_RING);
    float* ring2  = ring1 + (size_t)S * HH;
    const int smask = S - 1;
    const int TOT = T + F;

    // Gate lane mapping (A and B): wave w owns cells 25w..25w+24.
    // lanes 0-24: rows cell (i), cell+100 (f); lanes 32-56: cell+200 (g), cell+300 (o).
    const bool gi_lane = (l < 25);
    const bool go_lane = (l >= 32 && l < 57);
    const int cell = 25 * w + (gi_lane ? l : (go_lane ? (l - 32) : 0));
    const int gj0 = gi_lane ? cell : (go_lane ? cell + 200 : 0);
    const int gj1 = gi_lane ? cell + 100 : (go_lane ? cell + 300 : 0);

    if (blockIdx.x == 0) {
        // ================= A: layer-1 recurrence =================
        __shared__ __align__(16) float h1s[2][128];
        REP25(DECLW)
        {
            const float4* r0p = (const float4*)(w_hh1 + gj0 * HH);
            const float4* r1p = (const float4*)(w_hh1 + gj1 * HH);
            REP25(LOADW)
        }
        const float wx0 = w_ih1[gj0];
        const float wx1 = w_ih1[gj1];
        const float bi0 = b_ih1[gj0] + b_hh1[gj0];
        const float bi1 = b_ih1[gj1] + b_hh1[gj1];
        float cst = gi_lane ? enc_c[cell] : 0.f;
        if (tid < 128) {
            h1s[0][tid] = (tid < HH) ? enc_h[tid] : 0.f;
            h1s[1][tid] = 0.f;
        }
        __syncthreads();

        unsigned cp2 = 0, cy = 0;
        for (int t = 0; t < TOT; ++t) {
            // publish slot t-1: ring1 stores aged ~1 iteration -> vmcnt(0) cheap.
            VMCNT0();
            if (l == 0 && t > 0) stu(&aw[w], (unsigned)t);     // slots <= t-1 valid
            float x = 0.f;
            if (t < T) x = input[t];
            // ring1 overwrite guard: A2 consumed slot t-S when min(p2w) >= t-S+1
            if (t >= S) wait_min4(p2w, (unsigned)(t - S + 1), cp2);
            float hv0 = h1s[t & 1][l];
            float hv1 = h1s[t & 1][64 + l];    // lanes >=36 hold 0, never readlaned
            float a0 = 0.f, a1 = 0.f, b0 = 0.f, b1 = 0.f;
            REP25(DOTC)
            float accA = bi0 + a0 + a1;
            float accB = bi1 + b0 + b1;
            if (t >= T) {                       // future: dot done, now wait for y
                wait_ge(y_prog, (unsigned)(t - T + 1), cy);
                x = ld_f(&y_slot[t - T]);
            }
            accA = fmaf(x, wx0, accA);
            accB = fmaf(x, wx1, accB);
            float vA = go_lane ? fast_tanh(accA) : fast_sigm(accA);  // i or g
            float vB = fast_sigm(accB);                              // f or o
            float gg = __shfl_xor(vA, 32);
            float go = __shfl_xor(vB, 32);
            if (gi_lane) {
                cst = fmaf(vB, cst, vA * gg);
                float h = go * fast_tanh(cst);
                h1s[(t + 1) & 1][cell] = h;
                st_wt(&ring1[(size_t)(t & smask) * HH + cell], h);
            }
            bar();    // LDS-only drain; ring1 stores stay in flight across it
        }
        VMCNT0();
        if (l == 0) stu(&aw[w], (unsigned)TOT);
    } else if (blockIdx.x == 1) {
        // ===== A2: pre2 = w_ih2*h1 + biases. 4 independent waves, no barriers. =====
        const bool has2 = tid < (ROWS - NT);   // tid < 144 owns a second row
        const int j0 = tid, j1 = has2 ? NT + tid : 0;
        REP25(DECLW)
        {
            const float4* r0p = (const float4*)(w_ih2 + j0 * HH);
            const float4* r1p = (const float4*)(w_ih2 + j1 * HH);
            REP25(LOADW)
        }
        const float bi0 = b_ih2[j0] + b_hh2[j0];
        const float bi1 = b_ih2[j1] + b_hh2[j1];

        unsigned ca = 0, cb = 0;
        // ---- prologue: load slot 0
        wait_min4(aw, 1u, ca);
        float cv0 = ld_f(ring1 + l);
        float cv1 = (l < 36) ? ld_f(ring1 + 64 + l) : 0.f;
        // ---- pipelined encode: iter t stores slot t-1, prefetches slot t.
        // Counted vmcnt(2): <=2 outstanding proves stores up to slot t-3 acked.
        for (int t = 1; t < T; ++t) {
            VMCNT2();
            if (l == 0 && t >= 3) stu(&p2w[w], (unsigned)(t - 2));  // slots <= t-3 valid
            if (t - 1 >= S) wait_ge(b_prog, (unsigned)(t - S), cb); // overwrite guard
            wait_min4(aw, (unsigned)(t + 1), ca);                   // slot t readable
            const float* rp = ring1 + (size_t)(t & smask) * HH;
            float nv0 = ld_f(rp + l);
            float nv1 = (l < 36) ? ld_f(rp + 64 + l) : 0.f;
            float hv0 = cv0, hv1 = cv1;
            float a0 = 0.f, a1 = 0.f, b0 = 0.f, b1 = 0.f;
            REP25(DOTC)                                             // h(t-1)
            float* wp = ring2 + (size_t)((t - 1) & smask) * ROWS;
            st_wt(wp + j0, bi0 + a0 + a1);
            if (has2) st_wt(wp + j1, bi1 + b0 + b1);
            cv0 = nv0; cv1 = nv1;
        }
        // ---- boundary: drain pipeline, then slot T-1 straight.
        VMCNT0();
        if (l == 0) stu(&p2w[w], (unsigned)(T - 1));                // slots <= T-2 valid
        {
            if (T - 1 >= S) wait_ge(b_prog, (unsigned)(T - S), cb);
            float hv0 = cv0, hv1 = cv1;
            float a0 = 0.f, a1 = 0.f, b0 = 0.f, b1 = 0.f;
            REP25(DOTC)                                             // h(T-1)
            float* wp = ring2 + (size_t)((T - 1) & smask) * ROWS;
            st_wt(wp + j0, bi0 + a0 + a1);
            if (has2) st_wt(wp + j1, bi1 + b0 + b1);
        }
        VMCNT0();
        if (l == 0) stu(&p2w[w], (unsigned)T);                      // slots <= T-1 valid
        // ---- future: straight mode (serial chain needs same-step data).
        for (int t = T; t < TOT; ++t) {
            if (t >= S) wait_ge(b_prog, (unsigned)(t - S + 1), cb);
            wait_min4(aw, (unsigned)(t + 1), ca);
            const float* rp = ring1 + (size_t)(t & smask) * HH;
            float hv0 = ld_f(rp + l);
            float hv1 = (l < 36) ? ld_f(rp + 64 + l) : 0.f;
            float a0 = 0.f, a1 = 0.f, b0 = 0.f, b1 = 0.f;
            REP25(DOTC)
            float* wp = ring2 + (size_t)(t & smask) * ROWS;
            st_wt(wp + j0, bi0 + a0 + a1);
            if (has2) st_wt(wp + j1, bi1 + b0 + b1);
            VMCNT0();
            if (l == 0) stu(&p2w[w], (unsigned)(t + 1));
        }
    } else {
        // ================= B: layer-2 recurrence + output =================
        __shared__ __align__(16) float h2s[2][128];
        __shared__ float yp2[2][4];
        REP25(DECLW)
        {
            const float4* r0p = (const float4*)(w_hh2 + gj0 * HH);
            const float4* r1p = (const float4*)(w_hh2 + gj1 * HH);
            REP25(LOADW)
        }
        const float wl = gi_lane ? w_lin[cell] : 0.f;
        const float bl = b_lin[0];
        float c2 = 0.f;
        if (tid < 128) { h2s[0][tid] = 0.f; h2s[1][tid] = 0.f; }
        __syncthreads();

        unsigned cpB = 0;
        for (int u = 0; u < TOT; ++u) {
            // Emit previous step's y right after its barrier.
            if (tid == 0 && u > 0) {
                const float* yq = yp2[(u - 1) & 1];
                float y = yq[0] + yq[1] + yq[2] + yq[3] + bl;
                stu(b_prog, (unsigned)u);        // ring2 slot u-1 consumed pre-barrier
                if (u - 1 >= T - 1) {
                    st_wt(&y_slot[(u - 1) - (T - 1)], y);
                    VMCNT0();                    // y_slot store acked before flag
                    stu(y_prog, (unsigned)(u - T + 1));
                }
                out[u - 1] = y;
            }
            float hv0 = h2s[u & 1][l];
            float hv1 = h2s[u & 1][64 + l];
            const float* pp = ring2 + (size_t)(u & smask) * ROWS;
            float preA, preB;
            float a0 = 0.f, a1 = 0.f, b0 = 0.f, b1 = 0.f;
            if (u < T) {     // encode: wait first so pre2 load latency hides under dot
                wait_min4(p2w, (unsigned)(u + 1), cpB);
                preA = ld_f(pp + gj0);
                preB = ld_f(pp + gj1);
                REP25(DOTC)
            } else {         // future: local dot first, then wait
                REP25(DOTC)
                wait_min4(p2w, (unsigned)(u + 1), cpB);
                preA = ld_f(pp + gj0);
                preB = ld_f(pp + gj1);
            }
            float accA = preA + a0 + a1;
            float accB = preB + b0 + b1;
            float vA = go_lane ? fast_tanh(accA) : fast_sigm(accA);
            float vB = fast_sigm(accB);
            float gg = __shfl_xor(vA, 32);
            float go = __shfl_xor(vB, 32);
            float py = 0.f;
            if (gi_lane) {
                c2 = fmaf(vB, c2, vA * gg);
                float h = go * fast_tanh(c2);
                h2s[(u + 1) & 1][cell] = h;
                py = h * wl;
            }
            py += __shfl_down(py, 32);
            py += __shfl_down(py, 16);
            py += __shfl_down(py, 8);
            py += __shfl_down(py, 4);
            py += __shfl_down(py, 2);
            py += __shfl_down(py, 1);
            if (l == 0) yp2[u & 1][w] = py;
            bar();
        }
        if (tid == 0) {   // final step's y
            const float* yq = yp2[(TOT - 1) & 1];
            out[TOT - 1] = yq[0] + yq[1] + yq[2] + yq[3] + bl;
        }
    }
}

extern "C" void kernel_launch(void* const* d_in, const int* in_sizes, int n_in,
                              void* d_out, int out_size, void* d_ws, size_t ws_size,
                              hipStream_t stream) {
    const float* input = (const float*)d_in[0];
    const float* enc_h = (const float*)d_in[1];
    const float* enc_c = (const float*)d_in[2];
    const float* w_ih1 = (const float*)d_in[3];
    const float* w_hh1 = (const float*)d_in[4];
    const float* b_ih1 = (const float*)d_in[5];
    const float* b_hh1 = (const float*)d_in[6];
    const float* w_ih2 = (const float*)d_in[7];
    const float* w_hh2 = (const float*)d_in[8];
    const float* b_ih2 = (const float*)d_in[9];
    const float* b_hh2 = (const float*)d_in[10];
    const float* w_lin = (const float*)d_in[11];
    const float* b_lin = (const float*)d_in[12];
    (void)n_in;

    int T = in_sizes[0];
    int F = out_size - T;
    if (F < 0) F = 0;

    // largest power-of-two ring slot count that fits both rings in d_ws
    int S = 16;
    while ((size_t)OFF_RING + (size_t)S * 2 * (HH + ROWS) * 4 <= ws_size && S < 8192)
        S <<= 1;

    decoder_kernel<<<dim3(3), dim3(NT), 0, stream>>>(
        input, enc_h, enc_c, w_ih1, w_hh1, b_ih1, b_hh1,
        w_ih2, w_hh2, b_ih2, b_hh2, w_lin, b_lin,
        (float*)d_out, (char*)d_ws, T, F, S);
}

// Round 5
// 15996.628 us; speedup vs baseline: 4.5099x; 1.0126x over previous
//
#include <hip/hip_runtime.h>
#include <math.h>

// 2-layer LSTM decoder, H=100, T=8192 encode + F=1024 future steps, fp32.
// Three persistent blocks (3 CUs), 256 threads (4 waves) each:
//   block 0 (A) : layer-1 recurrence. gates1 = w_ih1*x + w_hh1*h1 + b. h1 -> ring1.
//   block 1 (A2): feed-forward pre2 = w_ih2*h1 + biases. ring1 -> ring2.
//                 4 INDEPENDENT waves, no barriers, 1-deep load pipeline.
//   block 2 (B) : layer-2 recurrence gates2 = pre2 + w_hh2*h2; y = h2.w_lin + b.
//
// V5: DEFEAT LOAD REMATERIALIZATION. V3 (arrays, VGPR=124) and V4 (named
// float4 locals, VGPR=116) both failed to keep the 200 per-thread weight
// floats in registers: loop-invariant loads from const __restrict__ memory are
// rematerializable, so under pressure the RA re-loads them from L2 every
// iteration (200KB/CU/step ~ 3600 cy/step = the measured 1.68us/step; all
// stages L2-BW-bound). Fix:
//   (a) opacify each weight component with asm volatile("" : "+v"(w)) after
//       the one-time load -> defining op is opaque asm, NOT rematerializable;
//   (b) __attribute__((amdgpu_waves_per_eu(1,1))) -> full 512-VGPR budget,
//       scheduler stops targeting higher occupancy.
// Certificate: VGPR_Count must jump to ~250-290.
//
// Sync design (unchanged from V3/V4, proven correct):
//  * Cross-CU data via relaxed agent atomics; ordering via s_waitcnt vmcnt only
//    (producer: vmcnt(0) before flag store; consumer: vmcnt(0) after flag obs).
//    NO agent fences (they emit whole-L2 buffer_wbl2/inv - V2 regression).
//  * Per-wave progress flags aw[4]/p2w[4], consumer takes min4; producers
//    publish at top-of-next-iteration (store acks aged ~1 iter -> vmcnt free).
//  * A/B use raw s_barrier + lgkmcnt(0) (LDS-only drain, ring stores stay in
//    flight). A2: counted vmcnt(2) certify, 1-deep prefetch pipeline in encode,
//    straight mode in future.
//  * Flags monotone <= 9217 -> 0xAA workspace poison sanitizes to 0.

#define HH 100
#define NT 256
#define ROWS 400
#define SPIN_CAP 2000000u

#define OFF_AW     0       // unsigned aw[4]  : A per-wave publish counters
#define OFF_P2W    128     // unsigned p2w[4] : A2 per-wave publish counters
#define OFF_BPROG  256     // unsigned        : B consumption counter
#define OFF_YPROG  384     // unsigned        : y produced counter
#define OFF_YSLOT  512     // float[F+1]
#define OFF_RING   16384

#define VMCNT0() asm volatile("s_waitcnt vmcnt(0)" ::: "memory")
#define VMCNT2() asm volatile("s_waitcnt vmcnt(2)" ::: "memory")
#define LGKM0()  asm volatile("s_waitcnt lgkmcnt(0)" ::: "memory")
#define CLOB()   asm volatile("" ::: "memory")

__device__ __forceinline__ float rl(float v, int k) {
    return __int_as_float(__builtin_amdgcn_readlane(__float_as_int(v), k));
}
__device__ __forceinline__ unsigned san(unsigned v) { return v > 0x00FFFFFFu ? 0u : v; }
__device__ __forceinline__ unsigned ldu(const unsigned* p) {
    return san(__hip_atomic_load((unsigned*)p, __ATOMIC_RELAXED, __HIP_MEMORY_SCOPE_AGENT));
}
__device__ __forceinline__ void stu(unsigned* p, unsigned v) {
    __hip_atomic_store(p, v, __ATOMIC_RELAXED, __HIP_MEMORY_SCOPE_AGENT);
}
__device__ __forceinline__ float ld_f(const float* p) {
    return __hip_atomic_load((float*)p, __ATOMIC_RELAXED, __HIP_MEMORY_SCOPE_AGENT);
}
__device__ __forceinline__ void st_wt(float* p, float v) {
    __hip_atomic_store(p, v, __ATOMIC_RELAXED, __HIP_MEMORY_SCOPE_AGENT);
}
__device__ __forceinline__ void wait_ge(unsigned* p, unsigned need, unsigned& cache) {
    if (cache >= need) return;
    unsigned s = 0;
    do { cache = ldu(p); } while (cache < need && ++s < SPIN_CAP);
    VMCNT0();
}
__device__ __forceinline__ void wait_min4(unsigned* q, unsigned need, unsigned& cache) {
    if (cache >= need) return;
    unsigned s = 0;
    for (;;) {
        unsigned m0 = ldu(q), m1 = ldu(q + 1), m2 = ldu(q + 2), m3 = ldu(q + 3);
        unsigned a = m0 < m1 ? m0 : m1, b = m2 < m3 ? m2 : m3;
        cache = a < b ? a : b;
        if (cache >= need || ++s > SPIN_CAP) break;
    }
    VMCNT0();
}
// Raw workgroup barrier: LDS drain only (ring stores stay in flight).
__device__ __forceinline__ void bar() {
    LGKM0();
    __builtin_amdgcn_s_barrier();
    CLOB();
}
__device__ __forceinline__ float fast_sigm(float x) {
    return __builtin_amdgcn_rcpf(1.0f + __expf(-x));
}
__device__ __forceinline__ float fast_tanh(float x) {
    return fmaf(-2.0f, __builtin_amdgcn_rcpf(1.0f + __expf(2.0f * x)), 1.0f);
}
// Pin a loaded float4 into VGPRs: value now defined by opaque asm -> the RA
// cannot rematerialize the originating load inside the loop.
__device__ __forceinline__ void opq(float4& v) {
    asm volatile("" : "+v"(v.x), "+v"(v.y), "+v"(v.z), "+v"(v.w));
}

// ---- weight registers: 25 chunks x float4 x 2 rows, all NAMED locals ----
#define REP25(M) M(0) M(1) M(2) M(3) M(4) M(5) M(6) M(7) M(8) M(9) M(10) M(11) \
                 M(12) M(13) M(14) M(15) M(16) M(17) M(18) M(19) M(20) M(21) M(22) M(23) M(24)
#define DECLW(i) float4 W0_##i, W1_##i;
#define LOADW(i) W0_##i = r0p[i]; W1_##i = r1p[i];
#define OPW(i)   opq(W0_##i); opq(W1_##i);
// chunk i covers h[4i..4i+3]; i<16 from hv0 (lanes 4i..), i>=16 from hv1 (lanes 4(i-16)..)
#define DOTC(i) { \
    const float hsv = ((i) < 16) ? hv0 : hv1; \
    const int kb = ((i) < 16) ? (4 * (i)) : (4 * ((i) - 16)); \
    float h0 = rl(hsv, kb), h1 = rl(hsv, kb + 1), h2 = rl(hsv, kb + 2), h3 = rl(hsv, kb + 3); \
    a0 = fmaf(W0_##i.x, h0, a0); b0 = fmaf(W1_##i.x, h0, b0); \
    a1 = fmaf(W0_##i.y, h1, a1); b1 = fmaf(W1_##i.y, h1, b1); \
    a0 = fmaf(W0_##i.z, h2, a0); b0 = fmaf(W1_##i.z, h2, b0); \
    a1 = fmaf(W0_##i.w, h3, a1); b1 = fmaf(W1_##i.w, h3, b1); \
}

extern "C" __global__ void __launch_bounds__(NT)
__attribute__((amdgpu_waves_per_eu(1, 1)))
decoder_kernel(const float* __restrict__ input,
               const float* __restrict__ enc_h,
               const float* __restrict__ enc_c,
               const float* __restrict__ w_ih1,
               const float* __restrict__ w_hh1,
               const float* __restrict__ b_ih1,
               const float* __restrict__ b_hh1,
               const float* __restrict__ w_ih2,
               const float* __restrict__ w_hh2,
               const float* __restrict__ b_ih2,
               const float* __restrict__ b_hh2,
               const float* __restrict__ w_lin,
               const float* __restrict__ b_lin,
               float* __restrict__ out,
               char* __restrict__ ws,
               int T, int F, int S)
{
    const int tid = threadIdx.x;
    const int l = tid & 63;
    const int w = tid >> 6;
    unsigned* aw     = (unsigned*)(ws + OFF_AW);
    unsigned* p2w    = (unsigned*)(ws + OFF_P2W);
    unsigned* b_prog = (unsigned*)(ws + OFF_BPROG);
    unsigned* y_prog = (unsigned*)(ws + OFF_YPROG);
    float* y_slot = (float*)(ws + OFF_YSLOT);
    float* ring1  = (float*)(ws + OFF_RING);
    float* ring2  = ring1 + (size_t)S * HH;
    const int smask = S - 1;
    const int TOT = T + F;

    // Gate lane mapping (A and B): wave w owns cells 25w..25w+24.
    // lanes 0-24: rows cell (i), cell+100 (f); lanes 32-56: cell+200 (g), cell+300 (o).
    const bool gi_lane = (l < 25);
    const bool go_lane = (l >= 32 && l < 57);
    const int cell = 25 * w + (gi_lane ? l : (go_lane ? (l - 32) : 0));
    const int gj0 = gi_lane ? cell : (go_lane ? cell + 200 : 0);
    const int gj1 = gi_lane ? cell + 100 : (go_lane ? cell + 300 : 0);

    if (blockIdx.x == 0) {
        // ================= A: layer-1 recurrence =================
        __shared__ __align__(16) float h1s[2][128];
        REP25(DECLW)
        {
            const float4* r0p = (const float4*)(w_hh1 + gj0 * HH);
            const float4* r1p = (const float4*)(w_hh1 + gj1 * HH);
            REP25(LOADW)
        }
        REP25(OPW)
        const float wx0 = w_ih1[gj0];
        const float wx1 = w_ih1[gj1];
        const float bi0 = b_ih1[gj0] + b_hh1[gj0];
        const float bi1 = b_ih1[gj1] + b_hh1[gj1];
        float cst = gi_lane ? enc_c[cell] : 0.f;
        if (tid < 128) {
            h1s[0][tid] = (tid < HH) ? enc_h[tid] : 0.f;
            h1s[1][tid] = 0.f;
        }
        __syncthreads();

        unsigned cp2 = 0, cy = 0;
        for (int t = 0; t < TOT; ++t) {
            // publish slot t-1: ring1 stores aged ~1 iteration -> vmcnt(0) cheap.
            VMCNT0();
            if (l == 0 && t > 0) stu(&aw[w], (unsigned)t);     // slots <= t-1 valid
            float x = 0.f;
            if (t < T) x = input[t];
            // ring1 overwrite guard: A2 consumed slot t-S when min(p2w) >= t-S+1
            if (t >= S) wait_min4(p2w, (unsigned)(t - S + 1), cp2);
            float hv0 = h1s[t & 1][l];
            float hv1 = h1s[t & 1][64 + l];    // lanes >=36 hold 0, never readlaned
            float a0 = 0.f, a1 = 0.f, b0 = 0.f, b1 = 0.f;
            REP25(DOTC)
            float accA = bi0 + a0 + a1;
            float accB = bi1 + b0 + b1;
            if (t >= T) {                       // future: dot done, now wait for y
                wait_ge(y_prog, (unsigned)(t - T + 1), cy);
                x = ld_f(&y_slot[t - T]);
            }
            accA = fmaf(x, wx0, accA);
            accB = fmaf(x, wx1, accB);
            float vA = go_lane ? fast_tanh(accA) : fast_sigm(accA);  // i or g
            float vB = fast_sigm(accB);                              // f or o
            float gg = __shfl_xor(vA, 32);
            float go = __shfl_xor(vB, 32);
            if (gi_lane) {
                cst = fmaf(vB, cst, vA * gg);
                float h = go * fast_tanh(cst);
                h1s[(t + 1) & 1][cell] = h;
                st_wt(&ring1[(size_t)(t & smask) * HH + cell], h);
            }
            bar();    // LDS-only drain; ring1 stores stay in flight across it
        }
        VMCNT0();
        if (l == 0) stu(&aw[w], (unsigned)TOT);
    } else if (blockIdx.x == 1) {
        // ===== A2: pre2 = w_ih2*h1 + biases. 4 independent waves, no barriers. =====
        const bool has2 = tid < (ROWS - NT);   // tid < 144 owns a second row
        const int j0 = tid, j1 = has2 ? NT + tid : 0;
        REP25(DECLW)
        {
            const float4* r0p = (const float4*)(w_ih2 + j0 * HH);
            const float4* r1p = (const float4*)(w_ih2 + j1 * HH);
            REP25(LOADW)
        }
        REP25(OPW)
        const float bi0 = b_ih2[j0] + b_hh2[j0];
        const float bi1 = b_ih2[j1] + b_hh2[j1];

        unsigned ca = 0, cb = 0;
        // ---- prologue: load slot 0
        wait_min4(aw, 1u, ca);
        float cv0 = ld_f(ring1 + l);
        float cv1 = (l < 36) ? ld_f(ring1 + 64 + l) : 0.f;
        // ---- pipelined encode: iter t stores slot t-1, prefetches slot t.
        // Counted vmcnt(2): <=2 outstanding proves stores up to slot t-3 acked.
        for (int t = 1; t < T; ++t) {
            VMCNT2();
            if (l == 0 && t >= 3) stu(&p2w[w], (unsigned)(t - 2));  // slots <= t-3 valid
            if (t - 1 >= S) wait_ge(b_prog, (unsigned)(t - S), cb); // overwrite guard
            wait_min4(aw, (unsigned)(t + 1), ca);                   // slot t readable
            const float* rp = ring1 + (size_t)(t & smask) * HH;
            float nv0 = ld_f(rp + l);
            float nv1 = (l < 36) ? ld_f(rp + 64 + l) : 0.f;
            float hv0 = cv0, hv1 = cv1;
            float a0 = 0.f, a1 = 0.f, b0 = 0.f, b1 = 0.f;
            REP25(DOTC)                                             // h(t-1)
            float* wp = ring2 + (size_t)((t - 1) & smask) * ROWS;
            st_wt(wp + j0, bi0 + a0 + a1);
            if (has2) st_wt(wp + j1, bi1 + b0 + b1);
            cv0 = nv0; cv1 = nv1;
        }
        // ---- boundary: drain pipeline, then slot T-1 straight.
        VMCNT0();
        if (l == 0) stu(&p2w[w], (unsigned)(T - 1));                // slots <= T-2 valid
        {
            if (T - 1 >= S) wait_ge(b_prog, (unsigned)(T - S), cb);
            float hv0 = cv0, hv1 = cv1;
            float a0 = 0.f, a1 = 0.f, b0 = 0.f, b1 = 0.f;
            REP25(DOTC)                                             // h(T-1)
            float* wp = ring2 + (size_t)((T - 1) & smask) * ROWS;
            st_wt(wp + j0, bi0 + a0 + a1);
            if (has2) st_wt(wp + j1, bi1 + b0 + b1);
        }
        VMCNT0();
        if (l == 0) stu(&p2w[w], (unsigned)T);                      // slots <= T-1 valid
        // ---- future: straight mode (serial chain needs same-step data).
        for (int t = T; t < TOT; ++t) {
            if (t >= S) wait_ge(b_prog, (unsigned)(t - S + 1), cb);
            wait_min4(aw, (unsigned)(t + 1), ca);
            const float* rp = ring1 + (size_t)(t & smask) * HH;
            float hv0 = ld_f(rp + l);
            float hv1 = (l < 36) ? ld_f(rp + 64 + l) : 0.f;
            float a0 = 0.f, a1 = 0.f, b0 = 0.f, b1 = 0.f;
            REP25(DOTC)
            float* wp = ring2 + (size_t)(t & smask) * ROWS;
            st_wt(wp + j0, bi0 + a0 + a1);
            if (has2) st_wt(wp + j1, bi1 + b0 + b1);
            VMCNT0();
            if (l == 0) stu(&p2w[w], (unsigned)(t + 1));
        }
    } else {
        // ================= B: layer-2 recurrence + output =================
        __shared__ __align__(16) float h2s[2][128];
        __shared__ float yp2[2][4];
        REP25(DECLW)
        {
            const float4* r0p = (const float4*)(w_hh2 + gj0 * HH);
            const float4* r1p = (const float4*)(w_hh2 + gj1 * HH);
            REP25(LOADW)
        }
        REP25(OPW)
        const float wl = gi_lane ? w_lin[cell] : 0.f;
        const float bl = b_lin[0];
        float c2 = 0.f;
        if (tid < 128) { h2s[0][tid] = 0.f; h2s[1][tid] = 0.f; }
        __syncthreads();

        unsigned cpB = 0;
        for (int u = 0; u < TOT; ++u) {
            // Emit previous step's y right after its barrier.
            if (tid == 0 && u > 0) {
                const float* yq = yp2[(u - 1) & 1];
                float y = yq[0] + yq[1] + yq[2] + yq[3] + bl;
                stu(b_prog, (unsigned)u);        // ring2 slot u-1 consumed pre-barrier
                if (u - 1 >= T - 1) {
                    st_wt(&y_slot[(u - 1) - (T - 1)], y);
                    VMCNT0();                    // y_slot store acked before flag
                    stu(y_prog, (unsigned)(u - T + 1));
                }
                out[u - 1] = y;
            }
            float hv0 = h2s[u & 1][l];
            float hv1 = h2s[u & 1][64 + l];
            const float* pp = ring2 + (size_t)(u & smask) * ROWS;
            float preA, preB;
            float a0 = 0.f, a1 = 0.f, b0 = 0.f, b1 = 0.f;
            if (u < T) {     // encode: wait first so pre2 load latency hides under dot
                wait_min4(p2w, (unsigned)(u + 1), cpB);
                preA = ld_f(pp + gj0);
                preB = ld_f(pp + gj1);
                REP25(DOTC)
            } else {         // future: local dot first, then wait
                REP25(DOTC)
                wait_min4(p2w, (unsigned)(u + 1), cpB);
                preA = ld_f(pp + gj0);
                preB = ld_f(pp + gj1);
            }
            float accA = preA + a0 + a1;
            float accB = preB + b0 + b1;
            float vA = go_lane ? fast_tanh(accA) : fast_sigm(accA);
            float vB = fast_sigm(accB);
            float gg = __shfl_xor(vA, 32);
            float go = __shfl_xor(vB, 32);
            float py = 0.f;
            if (gi_lane) {
                c2 = fmaf(vB, c2, vA * gg);
                float h = go * fast_tanh(c2);
                h2s[(u + 1) & 1][cell] = h;
                py = h * wl;
            }
            py += __shfl_down(py, 32);
            py += __shfl_down(py, 16);
            py += __shfl_down(py, 8);
            py += __shfl_down(py, 4);
            py += __shfl_down(py, 2);
            py += __shfl_down(py, 1);
            if (l == 0) yp2[u & 1][w] = py;
            bar();
        }
        if (tid == 0) {   // final step's y
            const float* yq = yp2[(TOT - 1) & 1];
            out[TOT - 1] = yq[0] + yq[1] + yq[2] + yq[3] + bl;
        }
    }
}

extern "C" void kernel_launch(void* const* d_in, const int* in_sizes, int n_in,
                              void* d_out, int out_size, void* d_ws, size_t ws_size,
                              hipStream_t stream) {
    const float* input = (const float*)d_in[0];
    const float* enc_h = (const float*)d_in[1];
    const float* enc_c = (const float*)d_in[2];
    const float* w_ih1 = (const float*)d_in[3];
    const float* w_hh1 = (const float*)d_in[4];
    const float* b_ih1 = (const float*)d_in[5];
    const float* b_hh1 = (const float*)d_in[6];
    const float* w_ih2 = (const float*)d_in[7];
    const float* w_hh2 = (const float*)d_in[8];
    const float* b_ih2 = (const float*)d_in[9];
    const float* b_hh2 = (const float*)d_in[10];
    const float* w_lin = (const float*)d_in[11];
    const float* b_lin = (const float*)d_in[12];
    (void)n_in;

    int T = in_sizes[0];
    int F = out_size - T;
    if (F < 0) F = 0;

    // largest power-of-two ring slot count that fits both rings in d_ws
    int S = 16;
    while ((size_t)OFF_RING + (size_t)S * 2 * (HH + ROWS) * 4 <= ws_size && S < 8192)
        S <<= 1;

    decoder_kernel<<<dim3(3), dim3(NT), 0, stream>>>(
        input, enc_h, enc_c, w_ih1, w_hh1, b_ih1, b_hh1,
        w_ih2, w_hh2, b_ih2, b_hh2, w_lin, b_lin,
        (float*)d_out, (char*)d_ws, T, F, S);
}